// Round 2
// baseline (254.020 us; speedup 1.0000x reference)
//
#include <hip/hip_runtime.h>
#include <hip/hip_bf16.h>

// ChildSumTreeLSTM, complete binary tree heap layout (children of n: 2n+1, 2n+2).
// R12: R11 failed (2 blocks/CU never co-resided: b[32]=128 AGPR + 124 VGPR = 252
// regs/wave -> hard 2-waves/SIMD cap; occupancy flat at 19.6%, dur +8%). Grids
// reverted to R10. New: K_A uses kd2f_kernel, a 1-deep software pipeline fusing
// L1(t-1) with L0(t) in ONE barrier phase (3 barriers/tile -> 2) so the two
// independent MFMA+transcendental chains hide each other's latency (ILP instead
// of the impossible TLP). To fit the 256-reg/wave budget the f-gate B fragments
// are streamed from global (L2-resident) instead of register-resident
// (b[32]->b[24], frees 32 regs); L0-leaf runs mm-halves sequentially (12-reg acc).
// h0/c0 and parent-x LDS double-buffered; LDS total 65024 B. K_B/K_C unchanged
// from R10 (3-barrier kd2p, full b[32]).
// Bsw = fragment-stream-ordered [W/2 | U] (f-gate W unhalved), gates [i,o,u,f];
// child row r computes [x_par; h_child]@B^T, epilogue sums row pairs in-lane.

#define DEPTH 17
#define NTREE ((1 << DEPTH) - 1)  // 131071
#define DIM 128
#define XSTR 136  // bf16 LDS row stride (shorts) = 272 B (16B-aligned, 2-way banks = free)
#define HSTR 136
#define CSTR 132  // fp32 LDS row stride (floats)

typedef __attribute__((ext_vector_type(8))) short short8;
typedef __attribute__((ext_vector_type(4))) float float4v;

__device__ __forceinline__ float sigm(float v) {
    return __fdividef(1.0f, 1.0f + __expf(-v));
}
__device__ __forceinline__ float ftanh(float v) {
    v = fminf(15.0f, fmaxf(-15.0f, v));
    float e = __expf(2.0f * v);
    return __fdividef(e - 1.0f, e + 1.0f);
}

__device__ __forceinline__ unsigned short f2bf(float f) {
    union { float f; unsigned u; } a; a.f = f;
    unsigned u = a.u;
    return (unsigned short)((u + 0x7fffu + ((u >> 16) & 1u)) >> 16);  // RNE
}
__device__ __forceinline__ float bf2f(unsigned short s) {
    union { unsigned u; float f; } a; a.u = ((unsigned)s) << 16;
    return a.f;
}

struct WPtrs {
    const float* W[4];  const float* U[4];
    const float* bW[4]; const float* bU[4];
};

// Bsw[w][ks][g][lane][j] (w:8, ks:8, g:4, lane:64, j:8) = fragment-stream order.
__global__ __launch_bounds__(256) void prep_kernel(WPtrs p, unsigned short* __restrict__ Bsw,
                                                   float* __restrict__ biasWU, float* __restrict__ biasL) {
    int idx = blockIdx.x * 256 + threadIdx.x;  // 0 .. 131071
    int j = idx & 7;
    int lane = (idx >> 3) & 63;
    int g = (idx >> 9) & 3;
    int ks = (idx >> 11) & 7;
    int w = idx >> 14;
    int L = lane & 15, q = lane >> 4;
    int c = w * 16 + L;
    int k = ks * 32 + q * 8 + j;
    float v = (k < 128) ? p.W[g][c * 128 + k] * (g == 3 ? 1.0f : 0.5f)
                        : p.U[g][c * 128 + (k - 128)];
    Bsw[idx] = f2bf(v);
    if (idx < 512) {
        int gg = idx >> 7, cc = idx & 127;
        biasWU[idx] = p.bW[gg][cc] + p.bU[gg][cc];
        biasL[idx]  = p.bW[gg][cc];
    }
}

// L1 parent compute: 16 parents from 32 level-0 children (h0p/c0p in LDS) +
// parent x rows (xs1p, 16 rows). b[24] = gates i,o,u; f-gate streamed from bfbase.
__device__ __forceinline__ void l1_compute(
    const unsigned short* xs1p, const unsigned short* h0p, const unsigned short* c0p,
    unsigned short* hA1, float* cA1,
    const short8 (&b)[24], const unsigned short* __restrict__ bfbase,
    const float* __restrict__ biasWU, int L, int q, int ch) {
    float4v acc[2][4];
#pragma unroll
    for (int mm = 0; mm < 2; ++mm)
#pragma unroll
        for (int g = 0; g < 4; ++g) acc[mm][g] = (float4v){0.f, 0.f, 0.f, 0.f};
#pragma unroll
    for (int ks = 0; ks < 8; ++ks) {
        const int kk = ks * 32;
        short8 a[2];
#pragma unroll
        for (int mm = 0; mm < 2; ++mm) {
            if (kk < 128)
                a[mm] = *(const short8*)(xs1p + (8 * mm + (L >> 1)) * XSTR + kk + q * 8);
            else
                a[mm] = *(const short8*)(h0p + (16 * mm + L) * XSTR + (kk - 128) + q * 8);
        }
        const short8 bf = *(const short8*)(bfbase + ((size_t)ks << 11));
#pragma unroll
        for (int g = 0; g < 3; ++g)
#pragma unroll
            for (int mm = 0; mm < 2; ++mm)
                acc[mm][g] = __builtin_amdgcn_mfma_f32_16x16x32_bf16(a[mm], b[ks * 3 + g], acc[mm][g], 0, 0, 0);
#pragma unroll
        for (int mm = 0; mm < 2; ++mm)
            acc[mm][3] = __builtin_amdgcn_mfma_f32_16x16x32_bf16(a[mm], bf, acc[mm][3], 0, 0, 0);
    }
#pragma unroll
    for (int mm = 0; mm < 2; ++mm)
#pragma unroll
        for (int e = 0; e < 2; ++e) {
            const int nl = 8 * mm + 2 * q + e;
            const int r0 = 2 * e, r1 = 2 * e + 1;
            float iv = sigm(acc[mm][0][r0] + acc[mm][0][r1] + biasWU[ch]);
            float ov = sigm(acc[mm][1][r0] + acc[mm][1][r1] + biasWU[128 + ch]);
            float uv = ftanh(acc[mm][2][r0] + acc[mm][2][r1] + biasWU[256 + ch]);
            float fl = sigm(acc[mm][3][r0] + biasWU[384 + ch]);
            float fr = sigm(acc[mm][3][r1] + biasWU[384 + ch]);
            float cl = bf2f(c0p[(2 * nl) * XSTR + ch]);
            float cr = bf2f(c0p[(2 * nl + 1) * XSTR + ch]);
            float cv = iv * uv + fl * cl + fr * cr;
            cA1[nl * CSTR + ch] = cv;
            hA1[nl * XSTR + ch] = f2bf(ov * ftanh(cv));
        }
}

// ---------- fused leaf depth-2 kernel (K_A): pipeline L1(t-1) with L0(t) ----------
__global__ __launch_bounds__(512, 2) void kd2f_kernel(
    const float* __restrict__ x, const unsigned short* __restrict__ Bsw,
    const float* __restrict__ biasL, const float* __restrict__ biasWU,
    unsigned short* __restrict__ hbf, float* __restrict__ cbuf,
    int x0base, int x1base, int ntiles) {
    __shared__ __align__(16) unsigned short xs0[32 * XSTR];       // leaf x, tile t
    __shared__ __align__(16) unsigned short xs1[2][16 * XSTR];    // parent x, dbuf
    __shared__ __align__(16) unsigned short h0[2][32 * XSTR];     // level-0 h, dbuf
    __shared__ __align__(16) unsigned short c0[2][32 * XSTR];     // level-0 c, dbuf
    __shared__ __align__(16) unsigned short hA1[16 * XSTR];
    __shared__ __align__(16) float cA1[16 * CSTR];

    const int tid = threadIdx.x;
    const int w = tid >> 6, lane = tid & 63, L = lane & 15, q = lane >> 4;
    const int ch = w * 16 + L;

    // gates i,o,u register-resident (24 frags = 96 regs); f-gate streamed.
    short8 b[24];
#pragma unroll
    for (int ks = 0; ks < 8; ++ks)
#pragma unroll
        for (int g = 0; g < 3; ++g)
            b[ks * 3 + g] = *(const short8*)(Bsw + ((size_t)w << 14) + ((size_t)(ks * 4 + g) << 9) + lane * 8);
    const unsigned short* bfbase = Bsw + ((size_t)w << 14) + (3 << 9) + lane * 8;

    // x prefetch regs: 48 rows * 32 float4 = 1536 granules = 3/thread
    float4 pfx[3];
    {
        const long tt = blockIdx.x;
        const long n0 = (long)x0base + tt * 32, n1 = (long)x1base + tt * 16;
#pragma unroll
        for (int k = 0; k < 3; ++k) {
            const int i = tid + 512 * k;
            const int row = i >> 5, j = i & 31;
            const long node = (k < 2) ? (n0 + row) : (n1 + (row - 32));
            pfx[k] = *(const float4*)(x + (size_t)node * DIM + j * 4);
        }
    }

    for (int it = 0; it < ntiles; ++it) {
        const long tt = (long)it * gridDim.x + blockIdx.x;
        const int pc = it & 1;

        // publish prefetched x (bf16): rows 0..31 -> xs0, rows 32..47 -> xs1[pc]
#pragma unroll
        for (int k = 0; k < 3; ++k) {
            const int i = tid + 512 * k;
            const int row = i >> 5, j = i & 31;
            ushort4 o;
            o.x = f2bf(pfx[k].x); o.y = f2bf(pfx[k].y);
            o.z = f2bf(pfx[k].z); o.w = f2bf(pfx[k].w);
            if (k < 2)
                *(ushort4*)(xs0 + row * XSTR + j * 4) = o;
            else
                *(ushort4*)(xs1[pc] + (row - 32) * XSTR + j * 4) = o;
        }
        __syncthreads();  // B1

        // issue next tile's x prefetch (in flight across fused compute)
        if (it + 1 < ntiles) {
            const long tn = tt + gridDim.x;
            const long m0 = (long)x0base + tn * 32, m1 = (long)x1base + tn * 16;
#pragma unroll
            for (int k = 0; k < 3; ++k) {
                const int i = tid + 512 * k;
                const int row = i >> 5, j = i & 31;
                const long node = (k < 2) ? (m0 + row) : (m1 + (row - 32));
                pfx[k] = *(const float4*)(x + (size_t)node * DIM + j * 4);
            }
        }

        // ---- fused phase: L1(t-1) + L0(t) (independent chains, one region) ----
        if (it > 0)
            l1_compute(xs1[pc ^ 1], h0[pc ^ 1], c0[pc ^ 1], hA1, cA1,
                       b, bfbase, biasWU, L, q, ch);

        // L0 leaves of tile t (mm halves sequential: 12-reg acc each)
#pragma unroll
        for (int mm = 0; mm < 2; ++mm) {
            float4v acc[3];
#pragma unroll
            for (int g = 0; g < 3; ++g) acc[g] = (float4v){0.f, 0.f, 0.f, 0.f};
#pragma unroll
            for (int ks = 0; ks < 4; ++ks) {
                short8 a = *(const short8*)(xs0 + (16 * mm + L) * XSTR + ks * 32 + q * 8);
#pragma unroll
                for (int g = 0; g < 3; ++g)
                    acc[g] = __builtin_amdgcn_mfma_f32_16x16x32_bf16(a, b[ks * 3 + g], acc[g], 0, 0, 0);
            }
#pragma unroll
            for (int r = 0; r < 4; ++r) {
                const int nl = 16 * mm + q * 4 + r;
                float iv = sigm(2.f * acc[0][r] + biasL[ch]);
                float ov = sigm(2.f * acc[1][r] + biasL[128 + ch]);
                float uv = ftanh(2.f * acc[2][r] + biasL[256 + ch]);
                float cv = iv * uv;
                c0[pc][nl * XSTR + ch] = f2bf(cv);
                h0[pc][nl * XSTR + ch] = f2bf(ov * ftanh(cv));
            }
        }
        __syncthreads();  // B2

        // coalesced store of tile t-1's 16 level-1 rows
        if (it > 0) {
            const long pn1 = (long)x1base + (tt - gridDim.x) * 16;
            for (int i = tid; i < 16 * 16; i += 512) {
                const int row = i >> 4, g = i & 15;
                *(uint4*)(hbf + (size_t)(pn1 + row) * DIM + g * 8) = *(const uint4*)(hA1 + row * XSTR + g * 8);
            }
            for (int i = tid; i < 16 * 32; i += 512) {
                const int row = i >> 5, j = i & 31;
                *(float4*)(cbuf + (size_t)(pn1 + row) * DIM + j * 4) = *(const float4*)(cA1 + row * CSTR + j * 4);
            }
        }
    }

    // ---- drain: L1 of the last tile ----
    __syncthreads();  // protect hA1/cA1 against the in-loop store still reading
    {
        const long tl = (long)(ntiles - 1) * gridDim.x + blockIdx.x;
        const int pl = (ntiles - 1) & 1;
        l1_compute(xs1[pl], h0[pl], c0[pl], hA1, cA1, b, bfbase, biasWU, L, q, ch);
        __syncthreads();
        const long n1 = (long)x1base + tl * 16;
        for (int i = tid; i < 16 * 16; i += 512) {
            const int row = i >> 4, g = i & 15;
            *(uint4*)(hbf + (size_t)(n1 + row) * DIM + g * 8) = *(const uint4*)(hA1 + row * XSTR + g * 8);
        }
        for (int i = tid; i < 16 * 32; i += 512) {
            const int row = i >> 5, j = i & 31;
            *(float4*)(cbuf + (size_t)(n1 + row) * DIM + j * 4) = *(const float4*)(cA1 + row * CSTR + j * 4);
        }
    }
}

// ---------- persistent depth-2 kernel (non-leaf levels, unchanged R10) ----------
template <bool LEAF0>
__global__ __launch_bounds__(512, 2) void kd2p_kernel(
    const float* __restrict__ x, const unsigned short* __restrict__ Bsw,
    const float* __restrict__ biasL, const float* __restrict__ biasWU,
    unsigned short* __restrict__ hbf, float* __restrict__ cbuf,
    int x0base, int x1base, int ntiles) {
    __shared__ __align__(16) unsigned short xs[48 * XSTR];
    __shared__ __align__(16) unsigned short hc[LEAF0 ? 16 : 64 * XSTR];
    __shared__ __align__(16) unsigned short h0[32 * XSTR];
    __shared__ __align__(16) unsigned short c0[32 * XSTR];
    __shared__ __align__(16) unsigned short hA1[16 * XSTR];
    __shared__ __align__(16) float cA1[16 * CSTR];

    const int tid = threadIdx.x;
    const int w = tid >> 6, lane = tid & 63, L = lane & 15, q = lane >> 4;
    const int ch = w * 16 + L;

    short8 b[32];
#pragma unroll
    for (int t = 0; t < 32; ++t)
        b[t] = *(const short8*)(Bsw + ((size_t)w << 14) + (t << 9) + lane * 8);

    float4 pfx[3];
    {
        const long tt = blockIdx.x;
        const long n0 = (long)x0base + tt * 32, n1 = (long)x1base + tt * 16;
#pragma unroll
        for (int k = 0; k < 3; ++k) {
            const int i = tid + 512 * k;
            const int row = i >> 5, j = i & 31;
            const long node = (row < 32) ? (n0 + row) : (n1 + (row - 32));
            pfx[k] = *(const float4*)(x + (size_t)node * DIM + j * 4);
        }
    }

    for (int it = 0; it < ntiles; ++it) {
        const long tt = (long)it * gridDim.x + blockIdx.x;
        const long n0 = (long)x0base + tt * 32;
        const long n1 = (long)x1base + tt * 16;
        const long cb = 2 * n0 + 1;

#pragma unroll
        for (int k = 0; k < 3; ++k) {
            const int i = tid + 512 * k;
            const int row = i >> 5, j = i & 31;
            ushort4 o;
            o.x = f2bf(pfx[k].x); o.y = f2bf(pfx[k].y);
            o.z = f2bf(pfx[k].z); o.w = f2bf(pfx[k].w);
            *(ushort4*)(xs + row * XSTR + j * 4) = o;
        }
        if (!LEAF0) {
            for (int i = tid; i < 64 * 16; i += 512) {
                const int row = i >> 4, g = i & 15;
                *(uint4*)(hc + row * XSTR + g * 8) =
                    *(const uint4*)(hbf + (size_t)(cb + row) * DIM + g * 8);
            }
        }
        __syncthreads();  // B1

        if (it + 1 < ntiles) {
            const long tn = tt + gridDim.x;
            const long m0 = (long)x0base + tn * 32, m1 = (long)x1base + tn * 16;
#pragma unroll
            for (int k = 0; k < 3; ++k) {
                const int i = tid + 512 * k;
                const int row = i >> 5, j = i & 31;
                const long node = (row < 32) ? (m0 + row) : (m1 + (row - 32));
                pfx[k] = *(const float4*)(x + (size_t)node * DIM + j * 4);
            }
        }

        // ---- level 0: 32 nodes ----
        if (LEAF0) {
            float4v acc[2][3];
#pragma unroll
            for (int mm = 0; mm < 2; ++mm)
#pragma unroll
                for (int g = 0; g < 3; ++g) acc[mm][g] = (float4v){0.f, 0.f, 0.f, 0.f};
#pragma unroll
            for (int ks = 0; ks < 4; ++ks) {
                short8 a[2];
                a[0] = *(const short8*)(xs + L * XSTR + ks * 32 + q * 8);
                a[1] = *(const short8*)(xs + (16 + L) * XSTR + ks * 32 + q * 8);
#pragma unroll
                for (int g = 0; g < 3; ++g)
#pragma unroll
                    for (int mm = 0; mm < 2; ++mm)
                        acc[mm][g] = __builtin_amdgcn_mfma_f32_16x16x32_bf16(a[mm], b[ks * 4 + g], acc[mm][g], 0, 0, 0);
            }
#pragma unroll
            for (int mm = 0; mm < 2; ++mm)
#pragma unroll
                for (int r = 0; r < 4; ++r) {
                    const int nl = 16 * mm + q * 4 + r;
                    float iv = sigm(2.f * acc[mm][0][r] + biasL[ch]);
                    float ov = sigm(2.f * acc[mm][1][r] + biasL[128 + ch]);
                    float uv = ftanh(2.f * acc[mm][2][r] + biasL[256 + ch]);
                    float cv = iv * uv;
                    c0[nl * XSTR + ch] = f2bf(cv);
                    h0[nl * XSTR + ch] = f2bf(ov * ftanh(cv));
                }
        } else {
            for (int mc = 0; mc < 4; mc += 2) {
                float4v acc[2][4];
#pragma unroll
                for (int mm = 0; mm < 2; ++mm)
#pragma unroll
                    for (int g = 0; g < 4; ++g) acc[mm][g] = (float4v){0.f, 0.f, 0.f, 0.f};
#pragma unroll
                for (int ks = 0; ks < 8; ++ks) {
                    const int kk = ks * 32;
                    short8 a[2];
#pragma unroll
                    for (int mm = 0; mm < 2; ++mm) {
                        if (kk < 128)
                            a[mm] = *(const short8*)(xs + (8 * (mc + mm) + (L >> 1)) * XSTR + kk + q * 8);
                        else
                            a[mm] = *(const short8*)(hc + (16 * (mc + mm) + L) * XSTR + (kk - 128) + q * 8);
                    }
#pragma unroll
                    for (int g = 0; g < 4; ++g)
#pragma unroll
                        for (int mm = 0; mm < 2; ++mm)
                            acc[mm][g] = __builtin_amdgcn_mfma_f32_16x16x32_bf16(a[mm], b[ks * 4 + g], acc[mm][g], 0, 0, 0);
                }
#pragma unroll
                for (int mm = 0; mm < 2; ++mm)
#pragma unroll
                    for (int e = 0; e < 2; ++e) {
                        const int nl = 8 * (mc + mm) + 2 * q + e;
                        const int r0 = 2 * e, r1 = 2 * e + 1;
                        float iv = sigm(acc[mm][0][r0] + acc[mm][0][r1] + biasWU[ch]);
                        float ov = sigm(acc[mm][1][r0] + acc[mm][1][r1] + biasWU[128 + ch]);
                        float uv = ftanh(acc[mm][2][r0] + acc[mm][2][r1] + biasWU[256 + ch]);
                        float fl = sigm(acc[mm][3][r0] + biasWU[384 + ch]);
                        float fr = sigm(acc[mm][3][r1] + biasWU[384 + ch]);
                        float cl = cbuf[(size_t)(cb + 2 * nl) * DIM + ch];
                        float cr = cbuf[(size_t)(cb + 2 * nl + 1) * DIM + ch];
                        float cv = iv * uv + fl * cl + fr * cr;
                        c0[nl * XSTR + ch] = f2bf(cv);
                        h0[nl * XSTR + ch] = f2bf(ov * ftanh(cv));
                    }
            }
        }
        __syncthreads();  // B2

        // ---- level 1: 16 parents ----
        {
            float4v acc[2][4];
#pragma unroll
            for (int mm = 0; mm < 2; ++mm)
#pragma unroll
                for (int g = 0; g < 4; ++g) acc[mm][g] = (float4v){0.f, 0.f, 0.f, 0.f};
#pragma unroll
            for (int ks = 0; ks < 8; ++ks) {
                const int kk = ks * 32;
                short8 a[2];
#pragma unroll
                for (int mm = 0; mm < 2; ++mm) {
                    if (kk < 128)
                        a[mm] = *(const short8*)(xs + (32 + 8 * mm + (L >> 1)) * XSTR + kk + q * 8);
                    else
                        a[mm] = *(const short8*)(h0 + (16 * mm + L) * XSTR + (kk - 128) + q * 8);
                }
#pragma unroll
                for (int g = 0; g < 4; ++g)
#pragma unroll
                    for (int mm = 0; mm < 2; ++mm)
                        acc[mm][g] = __builtin_amdgcn_mfma_f32_16x16x32_bf16(a[mm], b[ks * 4 + g], acc[mm][g], 0, 0, 0);
            }
#pragma unroll
            for (int mm = 0; mm < 2; ++mm)
#pragma unroll
                for (int e = 0; e < 2; ++e) {
                    const int nl = 8 * mm + 2 * q + e;
                    const int r0 = 2 * e, r1 = 2 * e + 1;
                    float iv = sigm(acc[mm][0][r0] + acc[mm][0][r1] + biasWU[ch]);
                    float ov = sigm(acc[mm][1][r0] + acc[mm][1][r1] + biasWU[128 + ch]);
                    float uv = ftanh(acc[mm][2][r0] + acc[mm][2][r1] + biasWU[256 + ch]);
                    float fl = sigm(acc[mm][3][r0] + biasWU[384 + ch]);
                    float fr = sigm(acc[mm][3][r1] + biasWU[384 + ch]);
                    float cl = bf2f(c0[(2 * nl) * XSTR + ch]);
                    float cr = bf2f(c0[(2 * nl + 1) * XSTR + ch]);
                    float cv = iv * uv + fl * cl + fr * cr;
                    cA1[nl * CSTR + ch] = cv;
                    hA1[nl * XSTR + ch] = f2bf(ov * ftanh(cv));
                }
        }
        __syncthreads();  // B3

        for (int i = tid; i < 16 * 16; i += 512) {
            const int row = i >> 4, g = i & 15;
            *(uint4*)(hbf + (size_t)(n1 + row) * DIM + g * 8) = *(const uint4*)(hA1 + row * XSTR + g * 8);
        }
        for (int i = tid; i < 16 * 32; i += 512) {
            const int row = i >> 5, j = i & 31;
            *(float4*)(cbuf + (size_t)(n1 + row) * DIM + j * 4) = *(const float4*)(cA1 + row * CSTR + j * 4);
        }
    }
}

// ---------- k23: fused multi-level subtree (fp32 x staging) ----------
template <bool GCH>
__device__ __forceinline__ void internal_level(
    const unsigned short* xc,
    const unsigned short* hin_l, const float* cin_l,
    const unsigned short* __restrict__ hin_g, const float* __restrict__ cin_g, long cb,
    unsigned short* ho, int ho_str, float* co, int co_str, int cnt,
    const short8 (&b)[32], const float* __restrict__ biasWU,
    int L, int q, int ch) {
    const int rows = 2 * cnt;
    const int mt = (rows + 15) >> 4;
    for (int mc = 0; mc < mt; mc += 2) {
        const int mm_n = (mt - mc >= 2) ? 2 : 1;
        float4v acc[2][4];
#pragma unroll
        for (int mm = 0; mm < 2; ++mm)
#pragma unroll
            for (int g = 0; g < 4; ++g) acc[mm][g] = (float4v){0.f, 0.f, 0.f, 0.f};
#pragma unroll
        for (int ks = 0; ks < 8; ++ks) {
            const int kk = ks * 32;
            short8 a[2];
#pragma unroll
            for (int mm = 0; mm < 2; ++mm) {
                if (mm < mm_n) {
                    if (kk < 128) {
                        int xr = 8 * (mc + mm) + (L >> 1);
                        if (xr >= cnt) xr = 0;
                        a[mm] = *(const short8*)(xc + xr * XSTR + kk + q * 8);
                    } else if (!GCH) {
                        a[mm] = *(const short8*)(hin_l + (16 * (mc + mm) + L) * HSTR + (kk - 128) + q * 8);
                    } else {
                        a[mm] = *(const short8*)(hin_g + (size_t)(cb + 16 * (mc + mm) + L) * DIM + (kk - 128) + q * 8);
                    }
                }
            }
#pragma unroll
            for (int g = 0; g < 4; ++g)
#pragma unroll
                for (int mm = 0; mm < 2; ++mm)
                    if (mm < mm_n)
                        acc[mm][g] = __builtin_amdgcn_mfma_f32_16x16x32_bf16(a[mm], b[ks * 4 + g], acc[mm][g], 0, 0, 0);
        }
#pragma unroll
        for (int mm = 0; mm < 2; ++mm)
#pragma unroll
            for (int e = 0; e < 2; ++e) {
                if (mm < mm_n) {
                    const int nl = 8 * (mc + mm) + 2 * q + e;
                    if (nl < cnt) {
                        const int r0 = 2 * e, r1 = 2 * e + 1;
                        float iv = sigm(acc[mm][0][r0] + acc[mm][0][r1] + biasWU[ch]);
                        float ov = sigm(acc[mm][1][r0] + acc[mm][1][r1] + biasWU[128 + ch]);
                        float uv = ftanh(acc[mm][2][r0] + acc[mm][2][r1] + biasWU[256 + ch]);
                        float fl = sigm(acc[mm][3][r0] + biasWU[384 + ch]);
                        float fr = sigm(acc[mm][3][r1] + biasWU[384 + ch]);
                        float cl, cr;
                        if (!GCH) {
                            cl = cin_l[(2 * nl) * CSTR + ch];
                            cr = cin_l[(2 * nl + 1) * CSTR + ch];
                        } else {
                            cl = cin_g[(size_t)(cb + 2 * nl) * DIM + ch];
                            cr = cin_g[(size_t)(cb + 2 * nl + 1) * DIM + ch];
                        }
                        float cv = iv * uv + fl * cl + fr * cr;
                        co[nl * co_str + ch] = cv;
                        ho[nl * ho_str + ch] = f2bf(ov * ftanh(cv));
                    }
                }
            }
    }
}

// K_D: C=32, NL=6, d0=10 (32 blocks, root -> global). K_E: C=16, NL=5, d0=4, PROJ.
template <int C, int NL, bool PROJ>
__global__ __launch_bounds__(512, 2) void k23_kernel(
    const float* __restrict__ x, const unsigned short* __restrict__ Bsw,
    const float* __restrict__ biasWU, unsigned short* __restrict__ hbf,
    float* __restrict__ cbuf, int d0,
    const float* __restrict__ Wp, const float* __restrict__ bWp,
    float* __restrict__ out) {
    constexpr int TOTX = 2 * C - (C >> (NL - 1));
    constexpr int AR = (C < 16) ? 16 : C;
    __shared__ __align__(16) unsigned short xs[TOTX * XSTR];
    __shared__ __align__(16) unsigned short hA[AR * HSTR];
    __shared__ __align__(16) unsigned short hB[16 * HSTR];
    __shared__ __align__(16) float cA[AR * CSTR];
    __shared__ __align__(16) float cB[16 * CSTR];
    __shared__ float red[4][128];

    const int tid = threadIdx.x;
    const int w = tid >> 6, lane = tid & 63, L = lane & 15, q = lane >> 4;
    const int ch = w * 16 + L;

    short8 b[32];
#pragma unroll
    for (int t = 0; t < 32; ++t)
        b[t] = *(const short8*)(Bsw + ((size_t)w << 14) + (t << 9) + lane * 8);

    {
        int xoff = 0;
#pragma unroll
        for (int l = 0; l < NL; ++l) {
            const int rows = C >> l;
            const long base = ((1 << (d0 - l)) - 1) + (long)blockIdx.x * rows;
            for (int i = tid; i < rows * 32; i += 512) {
                const int row = i >> 5, j = i & 31;
                float4 v = *(const float4*)(x + (size_t)(base + row) * DIM + j * 4);
                ushort4 o;
                o.x = f2bf(v.x); o.y = f2bf(v.y); o.z = f2bf(v.z); o.w = f2bf(v.w);
                *(ushort4*)(xs + (xoff + row) * XSTR + j * 4) = o;
            }
            xoff += rows;
        }
    }
    __syncthreads();

    const long cb = ((1 << (d0 + 1)) - 1) + (long)blockIdx.x * (2 * C);
    internal_level<true>(xs, nullptr, nullptr, hbf, cbuf, cb,
                         hA, HSTR, cA, CSTR, C, b, biasWU, L, q, ch);
    __syncthreads();

    const unsigned short* hin = hA;
    const float* cin = cA;
    int xoff = C;
#pragma unroll
    for (int l = 1; l < NL; ++l) {
        const int cnt = C >> l;
        if (!PROJ && l == NL - 1) {
            const long ob = ((1 << (d0 - (NL - 1))) - 1) + (long)blockIdx.x;
            internal_level<false>(xs + xoff * XSTR, hin, cin, nullptr, nullptr, 0,
                                  hbf + (size_t)ob * DIM, DIM,
                                  cbuf + (size_t)ob * DIM, DIM, cnt, b, biasWU, L, q, ch);
        } else {
            unsigned short* ho = (l & 1) ? hB : hA;
            float* co = (l & 1) ? cB : cA;
            internal_level<false>(xs + xoff * XSTR, hin, cin, nullptr, nullptr, 0,
                                  ho, HSTR, co, CSTR, cnt, b, biasWU, L, q, ch);
            __syncthreads();
            hin = ho; cin = co;
        }
        xoff += cnt;
    }

    if (PROJ) {
        const int o = tid & 127, sg = tid >> 7;
        float pacc = 0.f;
#pragma unroll
        for (int jj = 0; jj < 8; ++jj) {
            const int k = sg * 32 + jj * 4;
            float4 wv = *(const float4*)(Wp + o * DIM + k);
            pacc += bf2f(hin[k]) * wv.x + bf2f(hin[k + 1]) * wv.y +
                    bf2f(hin[k + 2]) * wv.z + bf2f(hin[k + 3]) * wv.w;
        }
        red[sg][o] = pacc;
        __syncthreads();
        if (tid < 128) out[tid] = bWp[tid] + red[0][tid] + red[1][tid] + red[2][tid] + red[3][tid];
    }
}

extern "C" void kernel_launch(void* const* d_in, const int* in_sizes, int n_in,
                              void* d_out, int out_size, void* d_ws, size_t ws_size,
                              hipStream_t stream) {
    const float* x   = (const float*)d_in[0];
    const float* Wi  = (const float*)d_in[2];  const float* bWi = (const float*)d_in[3];
    const float* Ui  = (const float*)d_in[4];  const float* bUi = (const float*)d_in[5];
    const float* Wf  = (const float*)d_in[6];  const float* bWf = (const float*)d_in[7];
    const float* Uf  = (const float*)d_in[8];  const float* bUf = (const float*)d_in[9];
    const float* Wo  = (const float*)d_in[10]; const float* bWo = (const float*)d_in[11];
    const float* Uo  = (const float*)d_in[12]; const float* bUo = (const float*)d_in[13];
    const float* Wu  = (const float*)d_in[14]; const float* bWu = (const float*)d_in[15];
    const float* Uu  = (const float*)d_in[16]; const float* bUu = (const float*)d_in[17];
    const float* Wp  = (const float*)d_in[18]; const float* bWp = (const float*)d_in[19];

    // ws: Bsw (131072 bf16) | biasWU(512 f32) | biasL(512 f32) |
    //     cbuf (65536*128 f32 = 33.6 MB) | hbf (65536*128 bf16 = 16.8 MB)
    unsigned short* Bsw = (unsigned short*)d_ws;
    float* biasWU = (float*)(Bsw + 131072);
    float* biasL  = biasWU + 512;
    float* cbuf   = biasL + 512;
    unsigned short* hbf = (unsigned short*)(cbuf + (size_t)65536 * DIM);

    WPtrs p;
    p.W[0] = Wi; p.W[1] = Wo; p.W[2] = Wu; p.W[3] = Wf;
    p.U[0] = Ui; p.U[1] = Uo; p.U[2] = Uu; p.U[3] = Uf;
    p.bW[0] = bWi; p.bW[1] = bWo; p.bW[2] = bWu; p.bW[3] = bWf;
    p.bU[0] = bUi; p.bU[1] = bUo; p.bU[2] = bUu; p.bU[3] = bUf;

    prep_kernel<<<512, 256, 0, stream>>>(p, Bsw, biasWU, biasL);

    // K_A: d16 (leaves) + d15, 2048 tiles, persistent grid 256 x 8 tiles (fused pipeline).
    kd2f_kernel<<<256, 512, 0, stream>>>(x, Bsw, biasL, biasWU, hbf, cbuf,
                                         (1 << 16) - 1, (1 << 15) - 1, 8);
    // K_B: d14 + d13 (children = d15), 512 tiles, grid 256 x 2.
    kd2p_kernel<false><<<256, 512, 0, stream>>>(x, Bsw, biasL, biasWU, hbf, cbuf,
                                                (1 << 14) - 1, (1 << 13) - 1, 2);
    // K_C: d12 + d11 (children = d13), 128 tiles, grid 128 x 1.
    kd2p_kernel<false><<<128, 512, 0, stream>>>(x, Bsw, biasL, biasWU, hbf, cbuf,
                                                (1 << 12) - 1, (1 << 11) - 1, 1);
    // K_D: d10..d5 (children = d11), 32 blocks.
    k23_kernel<32, 6, false><<<32, 512, 0, stream>>>(x, Bsw, biasWU, hbf, cbuf, 10,
                                                     nullptr, nullptr, nullptr);
    // K_E: d4..d0 + projection (children = d5).
    k23_kernel<16, 5, true><<<1, 512, 0, stream>>>(x, Bsw, biasWU, hbf, cbuf, 4,
                                                   Wp, bWp, (float*)d_out);
}

// Round 3
// 243.335 us; speedup vs baseline: 1.0439x; 1.0439x over previous
//
#include <hip/hip_runtime.h>
#include <hip/hip_bf16.h>

// ChildSumTreeLSTM, complete binary tree heap layout (children of n: 2n+1, 2n+2).
// R13: revert to R10 compute bodies (R11 failed: b[32]=128 AGPR + 124 VGPR = 252
// regs/wave is a hard 2-waves/SIMD cap, 2 blocks/CU never co-resided; R12 failed:
// fused L0+L1 required streaming f-gate B from global inside the MFMA loop ->
// vmcnt serialization, VALUBusy 57->41, dur +43%). New in R13, both zero-register:
//  (1) kd2r: 3 barriers/tile -> 2. Store of tile t-1 moved into the post-B1
//      region of tile t (overlaps L0 compute). Only xs needs double-buffering
//      (L1(t) reads xs[pc] vs publish(t+1) writes xs[pc^1]); h0/c0/hc/hA1/cA1
//      stay single-buffered: every other write/read pair is separated by B1/B2.
//  (2) f2bf via native __bf16 cast -> v_cvt_pk_bf16_f32 (HW RNE, bit-identical)
//      instead of 5-op manual RNE. Applied everywhere.
// Bsw = fragment-stream-ordered [W/2 | U] (f-gate W unhalved), gates [i,o,u,f];
// child row r computes [x_par; h_child]@B^T, epilogue sums row pairs in-lane.

#define DEPTH 17
#define NTREE ((1 << DEPTH) - 1)  // 131071
#define DIM 128
#define XSTR 136  // bf16 LDS row stride (shorts) = 272 B (16B-aligned, 2-way banks = free)
#define HSTR 136
#define CSTR 132  // fp32 LDS row stride (floats)

typedef __attribute__((ext_vector_type(8))) short short8;
typedef __attribute__((ext_vector_type(4))) float float4v;

__device__ __forceinline__ float sigm(float v) {
    return __fdividef(1.0f, 1.0f + __expf(-v));
}
__device__ __forceinline__ float ftanh(float v) {
    v = fminf(15.0f, fmaxf(-15.0f, v));
    float e = __expf(2.0f * v);
    return __fdividef(e - 1.0f, e + 1.0f);
}

__device__ __forceinline__ unsigned short f2bf(float f) {
    __bf16 h = (__bf16)f;  // fptrunc f32->bf16, RNE -> v_cvt_pk_bf16_f32 on gfx950
    unsigned short r;
    __builtin_memcpy(&r, &h, 2);
    return r;
}
__device__ __forceinline__ float bf2f(unsigned short s) {
    union { unsigned u; float f; } a; a.u = ((unsigned)s) << 16;
    return a.f;
}

struct WPtrs {
    const float* W[4];  const float* U[4];
    const float* bW[4]; const float* bU[4];
};

// Bsw[w][ks][g][lane][j] (w:8, ks:8, g:4, lane:64, j:8) = fragment-stream order.
__global__ __launch_bounds__(256) void prep_kernel(WPtrs p, unsigned short* __restrict__ Bsw,
                                                   float* __restrict__ biasWU, float* __restrict__ biasL) {
    int idx = blockIdx.x * 256 + threadIdx.x;  // 0 .. 131071
    int j = idx & 7;
    int lane = (idx >> 3) & 63;
    int g = (idx >> 9) & 3;
    int ks = (idx >> 11) & 7;
    int w = idx >> 14;
    int L = lane & 15, q = lane >> 4;
    int c = w * 16 + L;
    int k = ks * 32 + q * 8 + j;
    float v = (k < 128) ? p.W[g][c * 128 + k] * (g == 3 ? 1.0f : 0.5f)
                        : p.U[g][c * 128 + (k - 128)];
    Bsw[idx] = f2bf(v);
    if (idx < 512) {
        int gg = idx >> 7, cc = idx & 127;
        biasWU[idx] = p.bW[gg][cc] + p.bU[gg][cc];
        biasL[idx]  = p.bW[gg][cc];
    }
}

// ---------- persistent depth-2 kernel, 2 barriers/tile ----------
// Tile = 32 level-0 nodes (at x0base + tt*32) + 16 level-1 parents (x1base + tt*16).
// LEAF0: level-0 = true leaves (K=128, gates i,o,u, logit=2*acc+bW).
// Per tile: publish(xs[pc],hc) | B1 | prefetch-issue + store(t-1) + L0 | B2 | L1.
template <bool LEAF0>
__global__ __launch_bounds__(512, 2) void kd2r_kernel(
    const float* __restrict__ x, const unsigned short* __restrict__ Bsw,
    const float* __restrict__ biasL, const float* __restrict__ biasWU,
    unsigned short* __restrict__ hbf, float* __restrict__ cbuf,
    int x0base, int x1base, int ntiles) {
    __shared__ __align__(16) unsigned short xs[2][48 * XSTR];  // dbuf: L1(t) reads vs publish(t+1) writes
    __shared__ __align__(16) unsigned short hc[LEAF0 ? 16 : 64 * XSTR];
    __shared__ __align__(16) unsigned short h0[32 * XSTR];
    __shared__ __align__(16) unsigned short c0[32 * XSTR];
    __shared__ __align__(16) unsigned short hA1[16 * XSTR];
    __shared__ __align__(16) float cA1[16 * CSTR];

    const int tid = threadIdx.x;
    const int w = tid >> 6, lane = tid & 63, L = lane & 15, q = lane >> 4;
    const int ch = w * 16 + L;

    short8 b[32];
#pragma unroll
    for (int t = 0; t < 32; ++t)
        b[t] = *(const short8*)(Bsw + ((size_t)w << 14) + (t << 9) + lane * 8);

    // x prefetch regs: 48 rows * 32 float4 = 1536 granules = 3/thread
    float4 pfx[3];
    {
        const long tt = blockIdx.x;
        const long n0 = (long)x0base + tt * 32, n1 = (long)x1base + tt * 16;
#pragma unroll
        for (int k = 0; k < 3; ++k) {
            const int i = tid + 512 * k;
            const int row = i >> 5, j = i & 31;
            const long node = (row < 32) ? (n0 + row) : (n1 + (row - 32));
            pfx[k] = *(const float4*)(x + (size_t)node * DIM + j * 4);
        }
    }

    for (int it = 0; it < ntiles; ++it) {
        const long tt = (long)it * gridDim.x + blockIdx.x;
        const long n0 = (long)x0base + tt * 32;
        const long n1 = (long)x1base + tt * 16;
        const long cb = 2 * n0 + 1;
        const int pc = it & 1;
        unsigned short* xsp = xs[pc];

        // publish prefetched x (converted to bf16)
#pragma unroll
        for (int k = 0; k < 3; ++k) {
            const int i = tid + 512 * k;
            const int row = i >> 5, j = i & 31;
            ushort4 o;
            o.x = f2bf(pfx[k].x); o.y = f2bf(pfx[k].y);
            o.z = f2bf(pfx[k].z); o.w = f2bf(pfx[k].w);
            *(ushort4*)(xsp + row * XSTR + j * 4) = o;
        }
        if (!LEAF0) {  // stage 64 child h rows (previous dispatch's output)
            for (int i = tid; i < 64 * 16; i += 512) {
                const int row = i >> 4, g = i & 15;
                *(uint4*)(hc + row * XSTR + g * 8) =
                    *(const uint4*)(hbf + (size_t)(cb + row) * DIM + g * 8);
            }
        }
        __syncthreads();  // B1

        // issue next tile's x prefetch (in flight across L0+L1 compute)
        if (it + 1 < ntiles) {
            const long tn = tt + gridDim.x;
            const long m0 = (long)x0base + tn * 32, m1 = (long)x1base + tn * 16;
#pragma unroll
            for (int k = 0; k < 3; ++k) {
                const int i = tid + 512 * k;
                const int row = i >> 5, j = i & 31;
                const long node = (row < 32) ? (m0 + row) : (m1 + (row - 32));
                pfx[k] = *(const float4*)(x + (size_t)node * DIM + j * 4);
            }
        }

        // store tile t-1's 16 level-1 rows (overlaps L0 compute; hA1/cA1 reads
        // complete before this wave reaches B2, and L1(t) writes hA1 after B2)
        if (it > 0) {
            const long pn1 = n1 - (long)gridDim.x * 16;
            for (int i = tid; i < 16 * 16; i += 512) {
                const int row = i >> 4, g = i & 15;
                *(uint4*)(hbf + (size_t)(pn1 + row) * DIM + g * 8) = *(const uint4*)(hA1 + row * XSTR + g * 8);
            }
            for (int i = tid; i < 16 * 32; i += 512) {
                const int row = i >> 5, j = i & 31;
                *(float4*)(cbuf + (size_t)(pn1 + row) * DIM + j * 4) = *(const float4*)(cA1 + row * CSTR + j * 4);
            }
        }

        // ---- level 0: 32 nodes ----
        if (LEAF0) {
            float4v acc[2][3];
#pragma unroll
            for (int mm = 0; mm < 2; ++mm)
#pragma unroll
                for (int g = 0; g < 3; ++g) acc[mm][g] = (float4v){0.f, 0.f, 0.f, 0.f};
#pragma unroll
            for (int ks = 0; ks < 4; ++ks) {
                short8 a[2];
                a[0] = *(const short8*)(xsp + L * XSTR + ks * 32 + q * 8);
                a[1] = *(const short8*)(xsp + (16 + L) * XSTR + ks * 32 + q * 8);
#pragma unroll
                for (int g = 0; g < 3; ++g)
#pragma unroll
                    for (int mm = 0; mm < 2; ++mm)
                        acc[mm][g] = __builtin_amdgcn_mfma_f32_16x16x32_bf16(a[mm], b[ks * 4 + g], acc[mm][g], 0, 0, 0);
            }
#pragma unroll
            for (int mm = 0; mm < 2; ++mm)
#pragma unroll
                for (int r = 0; r < 4; ++r) {
                    const int nl = 16 * mm + q * 4 + r;
                    float iv = sigm(2.f * acc[mm][0][r] + biasL[ch]);
                    float ov = sigm(2.f * acc[mm][1][r] + biasL[128 + ch]);
                    float uv = ftanh(2.f * acc[mm][2][r] + biasL[256 + ch]);
                    float cv = iv * uv;
                    c0[nl * XSTR + ch] = f2bf(cv);
                    h0[nl * XSTR + ch] = f2bf(ov * ftanh(cv));
                }
        } else {
            for (int mc = 0; mc < 4; mc += 2) {
                float4v acc[2][4];
#pragma unroll
                for (int mm = 0; mm < 2; ++mm)
#pragma unroll
                    for (int g = 0; g < 4; ++g) acc[mm][g] = (float4v){0.f, 0.f, 0.f, 0.f};
#pragma unroll
                for (int ks = 0; ks < 8; ++ks) {
                    const int kk = ks * 32;
                    short8 a[2];
#pragma unroll
                    for (int mm = 0; mm < 2; ++mm) {
                        if (kk < 128)
                            a[mm] = *(const short8*)(xsp + (8 * (mc + mm) + (L >> 1)) * XSTR + kk + q * 8);
                        else
                            a[mm] = *(const short8*)(hc + (16 * (mc + mm) + L) * XSTR + (kk - 128) + q * 8);
                    }
#pragma unroll
                    for (int g = 0; g < 4; ++g)
#pragma unroll
                        for (int mm = 0; mm < 2; ++mm)
                            acc[mm][g] = __builtin_amdgcn_mfma_f32_16x16x32_bf16(a[mm], b[ks * 4 + g], acc[mm][g], 0, 0, 0);
                }
#pragma unroll
                for (int mm = 0; mm < 2; ++mm)
#pragma unroll
                    for (int e = 0; e < 2; ++e) {
                        const int nl = 8 * (mc + mm) + 2 * q + e;
                        const int r0 = 2 * e, r1 = 2 * e + 1;
                        float iv = sigm(acc[mm][0][r0] + acc[mm][0][r1] + biasWU[ch]);
                        float ov = sigm(acc[mm][1][r0] + acc[mm][1][r1] + biasWU[128 + ch]);
                        float uv = ftanh(acc[mm][2][r0] + acc[mm][2][r1] + biasWU[256 + ch]);
                        float fl = sigm(acc[mm][3][r0] + biasWU[384 + ch]);
                        float fr = sigm(acc[mm][3][r1] + biasWU[384 + ch]);
                        float cl = cbuf[(size_t)(cb + 2 * nl) * DIM + ch];
                        float cr = cbuf[(size_t)(cb + 2 * nl + 1) * DIM + ch];
                        float cv = iv * uv + fl * cl + fr * cr;
                        c0[nl * XSTR + ch] = f2bf(cv);
                        h0[nl * XSTR + ch] = f2bf(ov * ftanh(cv));
                    }
            }
        }
        __syncthreads();  // B2

        // ---- level 1: 16 parents (children = level-0 in LDS); no trailing barrier:
        // next publish writes xs[pc^1] (dbuf) and hc (not read here); h0/c0 writes
        // of L0(t+1) are fenced by B1(t+1).
        {
            float4v acc[2][4];
#pragma unroll
            for (int mm = 0; mm < 2; ++mm)
#pragma unroll
                for (int g = 0; g < 4; ++g) acc[mm][g] = (float4v){0.f, 0.f, 0.f, 0.f};
#pragma unroll
            for (int ks = 0; ks < 8; ++ks) {
                const int kk = ks * 32;
                short8 a[2];
#pragma unroll
                for (int mm = 0; mm < 2; ++mm) {
                    if (kk < 128)
                        a[mm] = *(const short8*)(xsp + (32 + 8 * mm + (L >> 1)) * XSTR + kk + q * 8);
                    else
                        a[mm] = *(const short8*)(h0 + (16 * mm + L) * XSTR + (kk - 128) + q * 8);
                }
#pragma unroll
                for (int g = 0; g < 4; ++g)
#pragma unroll
                    for (int mm = 0; mm < 2; ++mm)
                        acc[mm][g] = __builtin_amdgcn_mfma_f32_16x16x32_bf16(a[mm], b[ks * 4 + g], acc[mm][g], 0, 0, 0);
            }
#pragma unroll
            for (int mm = 0; mm < 2; ++mm)
#pragma unroll
                for (int e = 0; e < 2; ++e) {
                    const int nl = 8 * mm + 2 * q + e;
                    const int r0 = 2 * e, r1 = 2 * e + 1;
                    float iv = sigm(acc[mm][0][r0] + acc[mm][0][r1] + biasWU[ch]);
                    float ov = sigm(acc[mm][1][r0] + acc[mm][1][r1] + biasWU[128 + ch]);
                    float uv = ftanh(acc[mm][2][r0] + acc[mm][2][r1] + biasWU[256 + ch]);
                    float fl = sigm(acc[mm][3][r0] + biasWU[384 + ch]);
                    float fr = sigm(acc[mm][3][r1] + biasWU[384 + ch]);
                    float cl = bf2f(c0[(2 * nl) * XSTR + ch]);
                    float cr = bf2f(c0[(2 * nl + 1) * XSTR + ch]);
                    float cv = iv * uv + fl * cl + fr * cr;
                    cA1[nl * CSTR + ch] = cv;
                    hA1[nl * XSTR + ch] = f2bf(ov * ftanh(cv));
                }
        }
    }

    // ---- drain: store the last tile's level-1 rows ----
    __syncthreads();
    {
        const long tl = (long)(ntiles - 1) * gridDim.x + blockIdx.x;
        const long n1 = (long)x1base + tl * 16;
        for (int i = tid; i < 16 * 16; i += 512) {
            const int row = i >> 4, g = i & 15;
            *(uint4*)(hbf + (size_t)(n1 + row) * DIM + g * 8) = *(const uint4*)(hA1 + row * XSTR + g * 8);
        }
        for (int i = tid; i < 16 * 32; i += 512) {
            const int row = i >> 5, j = i & 31;
            *(float4*)(cbuf + (size_t)(n1 + row) * DIM + j * 4) = *(const float4*)(cA1 + row * CSTR + j * 4);
        }
    }
}

// ---------- k23: fused multi-level subtree (fp32 x staging) ----------
template <bool GCH>
__device__ __forceinline__ void internal_level(
    const unsigned short* xc,
    const unsigned short* hin_l, const float* cin_l,
    const unsigned short* __restrict__ hin_g, const float* __restrict__ cin_g, long cb,
    unsigned short* ho, int ho_str, float* co, int co_str, int cnt,
    const short8 (&b)[32], const float* __restrict__ biasWU,
    int L, int q, int ch) {
    const int rows = 2 * cnt;
    const int mt = (rows + 15) >> 4;
    for (int mc = 0; mc < mt; mc += 2) {
        const int mm_n = (mt - mc >= 2) ? 2 : 1;
        float4v acc[2][4];
#pragma unroll
        for (int mm = 0; mm < 2; ++mm)
#pragma unroll
            for (int g = 0; g < 4; ++g) acc[mm][g] = (float4v){0.f, 0.f, 0.f, 0.f};
#pragma unroll
        for (int ks = 0; ks < 8; ++ks) {
            const int kk = ks * 32;
            short8 a[2];
#pragma unroll
            for (int mm = 0; mm < 2; ++mm) {
                if (mm < mm_n) {
                    if (kk < 128) {
                        int xr = 8 * (mc + mm) + (L >> 1);
                        if (xr >= cnt) xr = 0;
                        a[mm] = *(const short8*)(xc + xr * XSTR + kk + q * 8);
                    } else if (!GCH) {
                        a[mm] = *(const short8*)(hin_l + (16 * (mc + mm) + L) * HSTR + (kk - 128) + q * 8);
                    } else {
                        a[mm] = *(const short8*)(hin_g + (size_t)(cb + 16 * (mc + mm) + L) * DIM + (kk - 128) + q * 8);
                    }
                }
            }
#pragma unroll
            for (int g = 0; g < 4; ++g)
#pragma unroll
                for (int mm = 0; mm < 2; ++mm)
                    if (mm < mm_n)
                        acc[mm][g] = __builtin_amdgcn_mfma_f32_16x16x32_bf16(a[mm], b[ks * 4 + g], acc[mm][g], 0, 0, 0);
        }
#pragma unroll
        for (int mm = 0; mm < 2; ++mm)
#pragma unroll
            for (int e = 0; e < 2; ++e) {
                if (mm < mm_n) {
                    const int nl = 8 * (mc + mm) + 2 * q + e;
                    if (nl < cnt) {
                        const int r0 = 2 * e, r1 = 2 * e + 1;
                        float iv = sigm(acc[mm][0][r0] + acc[mm][0][r1] + biasWU[ch]);
                        float ov = sigm(acc[mm][1][r0] + acc[mm][1][r1] + biasWU[128 + ch]);
                        float uv = ftanh(acc[mm][2][r0] + acc[mm][2][r1] + biasWU[256 + ch]);
                        float fl = sigm(acc[mm][3][r0] + biasWU[384 + ch]);
                        float fr = sigm(acc[mm][3][r1] + biasWU[384 + ch]);
                        float cl, cr;
                        if (!GCH) {
                            cl = cin_l[(2 * nl) * CSTR + ch];
                            cr = cin_l[(2 * nl + 1) * CSTR + ch];
                        } else {
                            cl = cin_g[(size_t)(cb + 2 * nl) * DIM + ch];
                            cr = cin_g[(size_t)(cb + 2 * nl + 1) * DIM + ch];
                        }
                        float cv = iv * uv + fl * cl + fr * cr;
                        co[nl * co_str + ch] = cv;
                        ho[nl * ho_str + ch] = f2bf(ov * ftanh(cv));
                    }
                }
            }
    }
}

// K_D: C=32, NL=6, d0=10 (32 blocks, root -> global). K_E: C=16, NL=5, d0=4, PROJ.
template <int C, int NL, bool PROJ>
__global__ __launch_bounds__(512, 2) void k23_kernel(
    const float* __restrict__ x, const unsigned short* __restrict__ Bsw,
    const float* __restrict__ biasWU, unsigned short* __restrict__ hbf,
    float* __restrict__ cbuf, int d0,
    const float* __restrict__ Wp, const float* __restrict__ bWp,
    float* __restrict__ out) {
    constexpr int TOTX = 2 * C - (C >> (NL - 1));
    constexpr int AR = (C < 16) ? 16 : C;
    __shared__ __align__(16) unsigned short xs[TOTX * XSTR];
    __shared__ __align__(16) unsigned short hA[AR * HSTR];
    __shared__ __align__(16) unsigned short hB[16 * HSTR];
    __shared__ __align__(16) float cA[AR * CSTR];
    __shared__ __align__(16) float cB[16 * CSTR];
    __shared__ float red[4][128];

    const int tid = threadIdx.x;
    const int w = tid >> 6, lane = tid & 63, L = lane & 15, q = lane >> 4;
    const int ch = w * 16 + L;

    short8 b[32];
#pragma unroll
    for (int t = 0; t < 32; ++t)
        b[t] = *(const short8*)(Bsw + ((size_t)w << 14) + (t << 9) + lane * 8);

    {
        int xoff = 0;
#pragma unroll
        for (int l = 0; l < NL; ++l) {
            const int rows = C >> l;
            const long base = ((1 << (d0 - l)) - 1) + (long)blockIdx.x * rows;
            for (int i = tid; i < rows * 32; i += 512) {
                const int row = i >> 5, j = i & 31;
                float4 v = *(const float4*)(x + (size_t)(base + row) * DIM + j * 4);
                ushort4 o;
                o.x = f2bf(v.x); o.y = f2bf(v.y); o.z = f2bf(v.z); o.w = f2bf(v.w);
                *(ushort4*)(xs + (xoff + row) * XSTR + j * 4) = o;
            }
            xoff += rows;
        }
    }
    __syncthreads();

    const long cb = ((1 << (d0 + 1)) - 1) + (long)blockIdx.x * (2 * C);
    internal_level<true>(xs, nullptr, nullptr, hbf, cbuf, cb,
                         hA, HSTR, cA, CSTR, C, b, biasWU, L, q, ch);
    __syncthreads();

    const unsigned short* hin = hA;
    const float* cin = cA;
    int xoff = C;
#pragma unroll
    for (int l = 1; l < NL; ++l) {
        const int cnt = C >> l;
        if (!PROJ && l == NL - 1) {
            const long ob = ((1 << (d0 - (NL - 1))) - 1) + (long)blockIdx.x;
            internal_level<false>(xs + xoff * XSTR, hin, cin, nullptr, nullptr, 0,
                                  hbf + (size_t)ob * DIM, DIM,
                                  cbuf + (size_t)ob * DIM, DIM, cnt, b, biasWU, L, q, ch);
        } else {
            unsigned short* ho = (l & 1) ? hB : hA;
            float* co = (l & 1) ? cB : cA;
            internal_level<false>(xs + xoff * XSTR, hin, cin, nullptr, nullptr, 0,
                                  ho, HSTR, co, CSTR, cnt, b, biasWU, L, q, ch);
            __syncthreads();
            hin = ho; cin = co;
        }
        xoff += cnt;
    }

    if (PROJ) {
        const int o = tid & 127, sg = tid >> 7;
        float pacc = 0.f;
#pragma unroll
        for (int jj = 0; jj < 8; ++jj) {
            const int k = sg * 32 + jj * 4;
            float4 wv = *(const float4*)(Wp + o * DIM + k);
            pacc += bf2f(hin[k]) * wv.x + bf2f(hin[k + 1]) * wv.y +
                    bf2f(hin[k + 2]) * wv.z + bf2f(hin[k + 3]) * wv.w;
        }
        red[sg][o] = pacc;
        __syncthreads();
        if (tid < 128) out[tid] = bWp[tid] + red[0][tid] + red[1][tid] + red[2][tid] + red[3][tid];
    }
}

extern "C" void kernel_launch(void* const* d_in, const int* in_sizes, int n_in,
                              void* d_out, int out_size, void* d_ws, size_t ws_size,
                              hipStream_t stream) {
    const float* x   = (const float*)d_in[0];
    const float* Wi  = (const float*)d_in[2];  const float* bWi = (const float*)d_in[3];
    const float* Ui  = (const float*)d_in[4];  const float* bUi = (const float*)d_in[5];
    const float* Wf  = (const float*)d_in[6];  const float* bWf = (const float*)d_in[7];
    const float* Uf  = (const float*)d_in[8];  const float* bUf = (const float*)d_in[9];
    const float* Wo  = (const float*)d_in[10]; const float* bWo = (const float*)d_in[11];
    const float* Uo  = (const float*)d_in[12]; const float* bUo = (const float*)d_in[13];
    const float* Wu  = (const float*)d_in[14]; const float* bWu = (const float*)d_in[15];
    const float* Uu  = (const float*)d_in[16]; const float* bUu = (const float*)d_in[17];
    const float* Wp  = (const float*)d_in[18]; const float* bWp = (const float*)d_in[19];

    // ws: Bsw (131072 bf16) | biasWU(512 f32) | biasL(512 f32) |
    //     cbuf (65536*128 f32 = 33.6 MB) | hbf (65536*128 bf16 = 16.8 MB)
    unsigned short* Bsw = (unsigned short*)d_ws;
    float* biasWU = (float*)(Bsw + 131072);
    float* biasL  = biasWU + 512;
    float* cbuf   = biasL + 512;
    unsigned short* hbf = (unsigned short*)(cbuf + (size_t)65536 * DIM);

    WPtrs p;
    p.W[0] = Wi; p.W[1] = Wo; p.W[2] = Wu; p.W[3] = Wf;
    p.U[0] = Ui; p.U[1] = Uo; p.U[2] = Uu; p.U[3] = Uf;
    p.bW[0] = bWi; p.bW[1] = bWo; p.bW[2] = bWu; p.bW[3] = bWf;
    p.bU[0] = bUi; p.bU[1] = bUo; p.bU[2] = bUu; p.bU[3] = bUf;

    prep_kernel<<<512, 256, 0, stream>>>(p, Bsw, biasWU, biasL);

    // K_A: d16 (leaves) + d15, 2048 tiles, persistent grid 256 x 8 tiles.
    kd2r_kernel<true><<<256, 512, 0, stream>>>(x, Bsw, biasL, biasWU, hbf, cbuf,
                                               (1 << 16) - 1, (1 << 15) - 1, 8);
    // K_B: d14 + d13 (children = d15), 512 tiles, grid 256 x 2.
    kd2r_kernel<false><<<256, 512, 0, stream>>>(x, Bsw, biasL, biasWU, hbf, cbuf,
                                                (1 << 14) - 1, (1 << 13) - 1, 2);
    // K_C: d12 + d11 (children = d13), 128 tiles, grid 128 x 1.
    kd2r_kernel<false><<<128, 512, 0, stream>>>(x, Bsw, biasL, biasWU, hbf, cbuf,
                                                (1 << 12) - 1, (1 << 11) - 1, 1);
    // K_D: d10..d5 (children = d11), 32 blocks.
    k23_kernel<32, 6, false><<<32, 512, 0, stream>>>(x, Bsw, biasWU, hbf, cbuf, 10,
                                                     nullptr, nullptr, nullptr);
    // K_E: d4..d0 + projection (children = d5).
    k23_kernel<16, 5, true><<<1, 512, 0, stream>>>(x, Bsw, biasWU, hbf, cbuf, 4,
                                                   Wp, bWp, (float*)d_out);
}